// Round 5
// baseline (233.594 us; speedup 1.0000x reference)
//
#include <hip/hip_runtime.h>
#include <cstdint>
#include <cstddef>

// Problem: B=64, R=196, L=512, K=768.
// Algebra: emb = p @ q^T + q^T = (1+p) outer q ==>
//   score[b,r,j] = (1+p[b,r]) * w[b,j],  w[b,:] = q[b,:] @ V
// out[b,r,:] = (1/Z_r) * sum_j exp(c_r*wm_j - M_r) * seq_emb[b,j,:] / sqrt(768)
//
// Round-5: seqT pre-transpose ELIMINATED (R3/R4 kprep stuck ~55us). kattn3
// stages fp32 seq -> bf16 swizzled LDS directly (pk cvt + 8B writes),
// overlapped with MFMA. Pipeline: krows (p+q) -> kw -> kattn3.

typedef __attribute__((ext_vector_type(8))) short short8;
typedef __attribute__((ext_vector_type(4))) float f32x4;

__device__ __forceinline__ unsigned short f32_to_bf16(float x) {
    unsigned int u = __float_as_uint(x);
    unsigned int r = (u + 0x7FFFu + ((u >> 16) & 1u)) >> 16;  // RNE
    return (unsigned short)r;
}
__device__ __forceinline__ float bf16_to_f32(unsigned short h) {
    return __uint_as_float(((unsigned int)h) << 16);
}

#if defined(__has_builtin)
#if __has_builtin(__builtin_amdgcn_cvt_pk_bf16_f32)
#define HAVE_PK_BF16 1
#endif
#endif

__device__ __forceinline__ unsigned int pk_bf16(float a, float b) {
#ifdef HAVE_PK_BF16
    typedef __attribute__((ext_vector_type(2))) __bf16 bf16x2;
    bf16x2 v = __builtin_amdgcn_cvt_pk_bf16_f32(a, b);
    return __builtin_bit_cast(unsigned int, v);
#else
    return (unsigned int)f32_to_bf16(a) | ((unsigned int)f32_to_bf16(b) << 16);
#endif
}

// ---- kernel 1: blocks 0..3135 -> p rows; blocks 3136..11327 -> q rows ------
__global__ __launch_bounds__(256) void krows(const float* __restrict__ img,
                                             const float* __restrict__ imgW,
                                             const float* __restrict__ imgBias,
                                             const float* __restrict__ seqe,
                                             const float* __restrict__ seqW,
                                             const float* __restrict__ seqBias,
                                             float* __restrict__ pv,
                                             float* __restrict__ qv) {
    int wv = threadIdx.x >> 6, lane = threadIdx.x & 63;
    if (blockIdx.x < 3136) {
        int row = blockIdx.x * 4 + wv;                    // 12544 p-rows, L=512
        const float4* x4 = (const float4*)(img + (size_t)row * 512);
        const float4* w4 = (const float4*)imgW;
        float s = 0.f;
#pragma unroll
        for (int i = 0; i < 2; ++i) {
            float4 a = x4[i * 64 + lane];
            float4 c = w4[i * 64 + lane];
            s += a.x * c.x + a.y * c.y + a.z * c.z + a.w * c.w;
        }
#pragma unroll
        for (int o = 32; o; o >>= 1) s += __shfl_xor(s, o, 64);
        if (lane == 0) pv[row] = tanhf(s + imgBias[0]);
    } else {
        int row = (blockIdx.x - 3136) * 4 + wv;           // 32768 q-rows, K=768
        const float4* x4 = (const float4*)(seqe + (size_t)row * 768);
        const float4* w4 = (const float4*)seqW;
        float s = 0.f;
#pragma unroll
        for (int i = 0; i < 3; ++i) {
            float4 a = x4[i * 64 + lane];
            float4 c = w4[i * 64 + lane];
            s += a.x * c.x + a.y * c.y + a.z * c.z + a.w * c.w;
        }
#pragma unroll
        for (int o = 32; o; o >>= 1) s += __shfl_xor(s, o, 64);
        if (lane == 0) qv[row] = tanhf(s + seqBias[0]);
    }
}

// ------- kernel 2: wm[b,j] = mask[b,j] ? (q[b,:] @ V[:,j]) : -1e30 ----------
__global__ __launch_bounds__(256) void kw(const float* __restrict__ qv,
                                          const float* __restrict__ V,
                                          const int* __restrict__ mask,
                                          float* __restrict__ wm) {
    __shared__ __align__(16) float sq[512];
    __shared__ __align__(16) float sacc[8][32][4];
    int b = blockIdx.x >> 2, jc = blockIdx.x & 3;
    int t = threadIdx.x;
    sq[t] = qv[b * 512 + t];
    sq[t + 256] = qv[b * 512 + t + 256];
    __syncthreads();
    int jt = t & 31, lg = t >> 5;
    const float4* V4 = (const float4*)V;
    int col4 = jc * 32 + jt;
    float ax = 0.f, ay = 0.f, az = 0.f, aw = 0.f;
    int lbase = lg * 64;
#pragma unroll 8
    for (int li = 0; li < 64; ++li) {
        int l = lbase + li;
        float qq = sq[l];
        float4 v = V4[(size_t)l * 128 + col4];
        ax += qq * v.x; ay += qq * v.y; az += qq * v.z; aw += qq * v.w;
    }
    sacc[lg][jt][0] = ax; sacc[lg][jt][1] = ay;
    sacc[lg][jt][2] = az; sacc[lg][jt][3] = aw;
    __syncthreads();
    if (t < 32) {
        float sx = 0.f, sy = 0.f, sz = 0.f, sw = 0.f;
#pragma unroll
        for (int g = 0; g < 8; ++g) {
            sx += sacc[g][t][0]; sy += sacc[g][t][1];
            sz += sacc[g][t][2]; sw += sacc[g][t][3];
        }
        const int* mrow = mask + b * 512 + jc * 128 + t * 4;
        float4 o;
        o.x = mrow[0] ? sx : -1e30f;
        o.y = mrow[1] ? sy : -1e30f;
        o.z = mrow[2] ? sz : -1e30f;
        o.w = mrow[3] ? sw : -1e30f;
        ((float4*)(wm + b * 512 + jc * 128))[t] = o;
    }
}

// ------- kernel 3: softmax-weights (regs) x fp32-seq staged to bf16 LDS -----
// grid raw 0..1535, XCD swizzle: rt-siblings of (b,nt) are 8 apart -> same XCD.
// Per chunk ch: stage seq[b, ch*64+j, nb+k] (64j x 128k fp32) -> bf16 LDS
// [k][j] with XOR swizzle, double-buffered; MFMA reads ds_read_b128.
__global__ __launch_bounds__(256, 2) void kattn3(const float* __restrict__ seq,
                                                 const float* __restrict__ p,
                                                 const float* __restrict__ wm,
                                                 float* __restrict__ out) {
    __shared__ __align__(16) unsigned short sB[2][128 * 64];  // 2 x 16 KB
    __shared__ __align__(16) float swm[512];
    __shared__ float sinvz[64];
    __shared__ float sred[16];

    int raw = blockIdx.x;
    int g  = ((raw >> 5) << 3) + (raw & 7);           // 0..383 = (b,nt)
    int rt = (raw >> 3) & 3;
    int b  = g / 6, nt = g - b * 6;
    int t  = threadIdx.x;
    int wv = t >> 6, lane = t & 63;
    int mm = lane & 15, q = lane >> 4;
    int nb = nt * 128;

    // --- phase 0a: wm -> LDS, block max/min over unmasked ---
    float v0 = wm[b * 512 + t];
    float v1 = wm[b * 512 + t + 256];
    swm[t] = v0; swm[t + 256] = v1;
    float lmax = fmaxf(v0, v1);
    float fa = (v0 > -1e29f) ? v0 : 1e30f;
    float fb = (v1 > -1e29f) ? v1 : 1e30f;
    float lmin = fminf(fa, fb);
#pragma unroll
    for (int o = 32; o; o >>= 1) {
        lmax = fmaxf(lmax, __shfl_xor(lmax, o, 64));
        lmin = fminf(lmin, __shfl_xor(lmin, o, 64));
    }
    if (lane == 0) { sred[wv] = lmax; sred[8 + wv] = lmin; }
    __syncthreads();
    float wmax = fmaxf(fmaxf(sred[0], sred[1]), fmaxf(sred[2], sred[3]));
    float wmin = fminf(fminf(sred[8], sred[9]), fminf(sred[10], sred[11]));

    int rl = wv * 16 + mm;
    int r  = rt * 64 + rl;
    bool valid = r < 196;
    int pidx = b * 196 + (valid ? r : 195);
    float c = 1.0f + p[pidx];
    float M = (c >= 0.f) ? c * wmax : c * wmin;

    // --- phase 0b: alpha-hat A-fragments in registers + Z ---
    short8 afrag[16];
    float zsum = 0.f;
    const f32x4* swm4 = (const f32x4*)swm;
#pragma unroll
    for (int tk = 0; tk < 16; ++tk) {
        int jb = tk * 32 + q * 8;
        f32x4 w0 = swm4[jb >> 2];
        f32x4 w1 = swm4[(jb >> 2) + 1];
        short8 af;
#pragma unroll
        for (int jj = 0; jj < 8; ++jj) {
            float ww = (jj < 4) ? w0[jj] : w1[jj - 4];
            float e = valid ? __expf(c * ww - M) : 0.f;
            unsigned short h = f32_to_bf16(e);
            zsum += bf16_to_f32(h);
            af[jj] = (short)h;
        }
        afrag[tk] = af;
    }
    zsum += __shfl_xor(zsum, 16, 64);
    zsum += __shfl_xor(zsum, 32, 64);
    if (q == 0) sinvz[rl] = 1.0f / zsum;

    f32x4 acc[8];
#pragma unroll
    for (int s = 0; s < 8; ++s) acc[s] = (f32x4){0.f, 0.f, 0.f, 0.f};

    // --- staging: fp32 seq -> bf16 swizzled LDS [k][j], 8B writes ---
    // thread: quad=t>>4 -> 4 j-rows (quad*4..+3); kseg=t&15 -> k nibbles.
    int quad = t >> 4, kseg = t & 15;
    int g8 = quad >> 1, sub = quad & 1;               // j-group, 4-j half
    const float* seqb = seq + (size_t)b * 512 * 768 + nb;
    auto stage = [&](int ch, int buf) {
        unsigned short* sb = sB[buf];
        const float* src = seqb + (size_t)(ch * 64 + quad * 4) * 768;
#pragma unroll
        for (int rp = 0; rp < 2; ++rp) {
            int k0 = rp * 64 + kseg * 4;
            float4 r0 = *(const float4*)(src + 0 * 768 + k0);
            float4 r1 = *(const float4*)(src + 1 * 768 + k0);
            float4 r2 = *(const float4*)(src + 2 * 768 + k0);
            float4 r3 = *(const float4*)(src + 3 * 768 + k0);
            float a0[4] = {r0.x, r0.y, r0.z, r0.w};
            float a1[4] = {r1.x, r1.y, r1.z, r1.w};
            float a2[4] = {r2.x, r2.y, r2.z, r2.w};
            float a3[4] = {r3.x, r3.y, r3.z, r3.w};
#pragma unroll
            for (int i = 0; i < 4; ++i) {
                int k = k0 + i;
                int sw = (k ^ (k >> 3)) & 7;
                uint2 v;
                v.x = pk_bf16(a0[i], a1[i]);
                v.y = pk_bf16(a2[i], a3[i]);
                *(uint2*)(sb + k * 64 + ((g8 ^ sw) << 3) + (sub << 2)) = v;
            }
        }
    };

    __syncthreads();
    stage(0, 0);
    __syncthreads();
#pragma unroll
    for (int ch = 0; ch < 8; ++ch) {
        if (ch < 7) stage(ch + 1, (ch + 1) & 1);
        const unsigned short* cb = sB[ch & 1];
#pragma unroll
        for (int kk = 0; kk < 2; ++kk) {
            short8 bfr[8];
#pragma unroll
            for (int s = 0; s < 8; ++s) {
                int n = s * 16 + mm;
                int sw = (n ^ (n >> 3)) & 7;
                bfr[s] = *(const short8*)(cb + n * 64 + ((((kk << 2) + q) ^ sw) << 3));
            }
#pragma unroll
            for (int s = 0; s < 8; ++s)
                acc[s] = __builtin_amdgcn_mfma_f32_16x16x32_bf16(
                    afrag[(ch << 1) + kk], bfr[s], acc[s], 0, 0, 0);
        }
        __syncthreads();
    }

    // --- epilogue: D layout col=mm, row=q*4+reg ---
    const float invsqrtk = 0.036084391824351615f;
#pragma unroll
    for (int reg = 0; reg < 4; ++reg) {
        int row = q * 4 + reg;
        int rr = rt * 64 + wv * 16 + row;
        if (rr < 196) {
            float scale = sinvz[wv * 16 + row] * invsqrtk;
            float* op = out + (size_t)(b * 196 + rr) * 768 + nb + mm;
#pragma unroll
            for (int s = 0; s < 8; ++s)
                op[s * 16] = acc[s][reg] * scale;
        }
    }
}

extern "C" void kernel_launch(void* const* d_in, const int* in_sizes, int n_in,
                              void* d_out, int out_size, void* d_ws, size_t ws_size,
                              hipStream_t stream) {
    const float* image_emb = (const float*)d_in[0];
    const float* seq_emb   = (const float*)d_in[1];
    const int*   mask      = (const int*)d_in[2];
    const float* image_W   = (const float*)d_in[3];
    const float* image_b   = (const float*)d_in[4];
    const float* seq_W     = (const float*)d_in[5];
    const float* seq_b     = (const float*)d_in[6];
    const float* V         = (const float*)d_in[7];
    float* out = (float*)d_out;

    float* p_ws  = (float*)d_ws;                             // 12544 f
    float* q_ws  = (float*)((char*)d_ws + (64 << 10));       // 32768 f
    float* wm_ws = (float*)((char*)d_ws + (192 << 10));      // 32768 f

    krows<<<dim3(11328), dim3(256), 0, stream>>>(image_emb, image_W, image_b,
                                                 seq_emb, seq_W, seq_b,
                                                 p_ws, q_ws);
    kw<<<dim3(256), dim3(256), 0, stream>>>(q_ws, V, mask, wm_ws);
    kattn3<<<dim3(1536), dim3(256), 0, stream>>>(seq_emb, p_ws, wm_ws, out);
}